// Round 4
// baseline (1051.979 us; speedup 1.0000x reference)
//
#include <hip/hip_runtime.h>
#include <hip/hip_bf16.h>

// Problem constants (fixed by reference)
#define Nn     20000
#define Ee     240000
#define Gg     64
#define Ff     768
#define H1c    128
#define PEc    32
#define Dd     160      // H1 + PE
#define HEADSc 5
#define HCc    800      // HEADS * D
#define H2c    128
#define OUTc   16
#define ETot   (Ee + Nn)  // edges + self loops = 260000
#define NEG_SLOPE_F 0.2f

typedef short bf16x8 __attribute__((ext_vector_type(8)));
typedef float f32x4 __attribute__((ext_vector_type(4)));
typedef unsigned int u32;

// ---- bf16 split helpers (round-to-nearest-even) ----
__device__ __forceinline__ unsigned short bf_hi_rn(float v) {
    unsigned int u = __float_as_uint(v);
    return (unsigned short)((u + 0x7FFFu + ((u >> 16) & 1u)) >> 16);
}
__device__ __forceinline__ void bsplit(float v, unsigned short& h, unsigned short& l) {
    unsigned short hh = bf_hi_rn(v);
    float hf = __uint_as_float(((unsigned int)hh) << 16);
    l = bf_hi_rn(v - hf);
    h = hh;
}

// async global->LDS, 16 B per lane; LDS dest = wave-uniform base + lane*16
__device__ __forceinline__ void gl_lds16(const unsigned short* g, unsigned short* l) {
    __builtin_amdgcn_global_load_lds(
        (const __attribute__((address_space(1))) u32*)g,
        (__attribute__((address_space(3))) u32*)l, 16, 0, 0);
}

// ---------------------------------------------------------------------------
// Split fp32 array -> bf16 hi/lo arrays (same layout), vectorized by 4
// ---------------------------------------------------------------------------
__global__ void asplit_kernel(const float* __restrict__ A, unsigned short* __restrict__ Ah,
                              unsigned short* __restrict__ Al, int total4) {
    int i = blockIdx.x * 256 + threadIdx.x;
    if (i < total4) {
        float4 v = ((const float4*)A)[i];
        ushort4 h4, l4;
        bsplit(v.x, h4.x, l4.x);
        bsplit(v.y, h4.y, l4.y);
        bsplit(v.z, h4.z, l4.z);
        bsplit(v.w, h4.w, l4.w);
        ((ushort4*)Ah)[i] = h4;
        ((ushort4*)Al)[i] = l4;
    }
}

// Weight transpose + split: W[K][N] fp32 -> Wh/Wl[N][K] bf16
__global__ void wsplit_kernel(const float* __restrict__ W, unsigned short* __restrict__ Wh,
                              unsigned short* __restrict__ Wl, int K, int N) {
    int i = blockIdx.x * 256 + threadIdx.x;
    if (i < K * N) {
        int k = i / N, n = i % N;
        unsigned short h, l;
        bsplit(W[i], h, l);
        Wh[(size_t)n * K + k] = h;
        Wl[(size_t)n * K + k] = l;
    }
}

// ---------------------------------------------------------------------------
// bf16x3 MFMA GEMM: C[MxN] = act(A[MxK] @ B[KxN] + bias)
// A as hi/lo bf16 row-major [M][lda]; B TRANSPOSED hi/lo [N][K].
// C = Ah@Bh + Ah@Bl + Al@Bh  (fp32 accum) -> ~fp32 precision.
// Staging via global_load_lds width=16 into unpadded [128][32] LDS tiles.
// grid.x = M-tiles (fastest), grid.y = N-tiles.
// ---------------------------------------------------------------------------
#define KCHUNK 32

// stage a 128x32 bf16 tile: wave w covers rows {w*16+p*64}, lane L -> +L*16 B
__device__ __forceinline__ void stage_tile(const unsigned short* __restrict__ gsrc, int ld,
                                           int row0, int maxRow, int k0,
                                           unsigned short* lbuf, int wave, int lane) {
    #pragma unroll
    for (int p = 0; p < 2; ++p) {
        int rb = wave * 16 + p * 64;
        int r = rb + (lane >> 2);
        int gr = min(row0 + r, maxRow);
        const unsigned short* g = gsrc + (size_t)gr * ld + k0 + (lane & 3) * 8;
        gl_lds16(g, lbuf + rb * 32);
    }
}

template<int OUT_MODE>
__global__ __launch_bounds__(256)
void gemm3_kernel(const unsigned short* __restrict__ Ah, const unsigned short* __restrict__ Al,
                  const unsigned short* __restrict__ Bh, const unsigned short* __restrict__ Bl,
                  const float* __restrict__ bias, float* __restrict__ C,
                  unsigned short* __restrict__ Ch, unsigned short* __restrict__ Cl,
                  int M, int N, int K, int lda, int ldc, int relu) {
    __shared__ __attribute__((aligned(16))) unsigned short As_h[128 * 32];
    __shared__ __attribute__((aligned(16))) unsigned short As_l[128 * 32];
    __shared__ __attribute__((aligned(16))) unsigned short Bs_h[128 * 32];
    __shared__ __attribute__((aligned(16))) unsigned short Bs_l[128 * 32];

    int tid = threadIdx.x;
    int m0 = blockIdx.x * 128, n0 = blockIdx.y * 128;
    int wave = tid >> 6, lane = tid & 63;
    int wm = (wave >> 1) * 64;
    int wn = (wave & 1) * 64;
    int fr = lane & 15;
    int fq = (lane >> 4) * 8;

    f32x4 acc[4][4] = {};

    for (int k0 = 0; k0 < K; k0 += KCHUNK) {
        stage_tile(Ah, lda, m0, M - 1, k0, As_h, wave, lane);
        stage_tile(Al, lda, m0, M - 1, k0, As_l, wave, lane);
        stage_tile(Bh, K,   n0, N - 1, k0, Bs_h, wave, lane);
        stage_tile(Bl, K,   n0, N - 1, k0, Bs_l, wave, lane);
        __syncthreads();

        bf16x8 a_h[4], a_l[4], b_h[4], b_l[4];
        #pragma unroll
        for (int i = 0; i < 4; ++i) {
            a_h[i] = *(const bf16x8*)&As_h[(wm + i * 16 + fr) * 32 + fq];
            a_l[i] = *(const bf16x8*)&As_l[(wm + i * 16 + fr) * 32 + fq];
        }
        #pragma unroll
        for (int j = 0; j < 4; ++j) {
            b_h[j] = *(const bf16x8*)&Bs_h[(wn + j * 16 + fr) * 32 + fq];
            b_l[j] = *(const bf16x8*)&Bs_l[(wn + j * 16 + fr) * 32 + fq];
        }
        #pragma unroll
        for (int j = 0; j < 4; ++j) {
            #pragma unroll
            for (int i = 0; i < 4; ++i) {
                acc[i][j] = __builtin_amdgcn_mfma_f32_16x16x32_bf16(a_h[i], b_h[j], acc[i][j], 0, 0, 0);
                acc[i][j] = __builtin_amdgcn_mfma_f32_16x16x32_bf16(a_h[i], b_l[j], acc[i][j], 0, 0, 0);
                acc[i][j] = __builtin_amdgcn_mfma_f32_16x16x32_bf16(a_l[i], b_h[j], acc[i][j], 0, 0, 0);
            }
        }
        __syncthreads();
    }

    // epilogue: C/D layout col=lane&15, row=(lane>>4)*4+reg  [m89/m91-verified]
    int cr = (lane >> 4) * 4, cc = lane & 15;
    #pragma unroll
    for (int i = 0; i < 4; ++i) {
        #pragma unroll
        for (int j = 0; j < 4; ++j) {
            int c = n0 + wn + j * 16 + cc;
            if (c >= N) continue;
            float bv = bias ? bias[c] : 0.f;
            #pragma unroll
            for (int reg = 0; reg < 4; ++reg) {
                int r = m0 + wm + i * 16 + cr + reg;
                if (r >= M) continue;
                float v = acc[i][j][reg] + bv;
                if (relu) v = fmaxf(v, 0.f);
                if (OUT_MODE == 0) {
                    C[(size_t)r * ldc + c] = v;
                } else {
                    unsigned short hh, ll;
                    bsplit(v, hh, ll);
                    Ch[(size_t)r * ldc + c] = hh;
                    Cl[(size_t)r * ldc + c] = ll;
                }
            }
        }
    }
}

// copy pe_enc into h splits cols [128:160)
__global__ void pe_copy_kernel(const float* __restrict__ pe, unsigned short* __restrict__ hh,
                               unsigned short* __restrict__ hl) {
    int i = blockIdx.x * 256 + threadIdx.x;
    if (i < Nn * PEc) {
        int n = i / PEc, j = i % PEc;
        unsigned short h, l;
        bsplit(pe[i], h, l);
        hh[(size_t)n * Dd + H1c + j] = h;
        hl[(size_t)n * Dd + H1c + j] = l;
    }
}

// count in-degree (real edges only)
__global__ void count_kernel(const int* __restrict__ eidx, int* __restrict__ cnt) {
    int e = blockIdx.x * 256 + threadIdx.x;
    if (e < Ee) atomicAdd(&cnt[eidx[Ee + e]], 1);
}

// ---- multi-block exclusive scan over (cnt[i]+1) ----
#define NBLK 79  // ceil(20000/256)
__global__ void scan1_kernel(const int* __restrict__ cnt, int* __restrict__ off,
                             int* __restrict__ bsum) {
    __shared__ int sh[256];
    int t = threadIdx.x, i = blockIdx.x * 256 + t;
    int v = (i < Nn) ? (cnt[i] + 1) : 0;
    sh[t] = v;
    __syncthreads();
    for (int ofs = 1; ofs < 256; ofs <<= 1) {
        int add = (t >= ofs) ? sh[t - ofs] : 0;
        __syncthreads();
        sh[t] += add;
        __syncthreads();
    }
    if (i < Nn) off[i] = sh[t] - v;
    if (t == 255) bsum[blockIdx.x] = sh[255];
}
__global__ void scan2_kernel(int* __restrict__ bsum) {
    if (threadIdx.x == 0) {
        int acc = 0;
        for (int b = 0; b < NBLK; ++b) { int v = bsum[b]; bsum[b] = acc; acc += v; }
    }
}
__global__ void scan3_kernel(const int* __restrict__ cnt, int* __restrict__ off,
                             int* __restrict__ nxt, float* __restrict__ dinv,
                             const int* __restrict__ bsum) {
    int i = blockIdx.x * 256 + threadIdx.x;
    if (i < Nn) {
        int o = off[i] + bsum[blockIdx.x];
        off[i] = o;
        nxt[i] = o;
        dinv[i] = rsqrtf((float)(cnt[i] + 1));
    }
    if (i == 0) off[Nn] = ETot;
}

// scatter edges (and self loops) into CSR by dst
__global__ void scatter_kernel(const int* __restrict__ eidx, int* __restrict__ nxt,
                               int* __restrict__ elist, int* __restrict__ edst) {
    int e = blockIdx.x * 256 + threadIdx.x;
    if (e < ETot) {
        int s, d;
        if (e < Ee) { s = eidx[e]; d = eidx[Ee + e]; }
        else        { s = e - Ee; d = s; }
        int slot = atomicAdd(&nxt[d], 1);
        elist[slot] = s;
        edst[slot] = d;
    }
}

// ---------------------------------------------------------------------------
// GATv2 scores: 2 edges per wave (lanes 0-31 / 32-63), float4, head-clean.
// ---------------------------------------------------------------------------
__global__ __launch_bounds__(256)
void score_kernel(const float* __restrict__ xl, const float* __restrict__ xr,
                  const float* __restrict__ att, const int* __restrict__ elist,
                  const int* __restrict__ edst, float* __restrict__ scoreS) {
    int w = blockIdx.x * 4 + (threadIdx.x >> 6);
    int lane = threadIdx.x & 63;
    int j = lane & 31;
    int slot = w * 2 + (lane >> 5);
    if (slot >= ETot) return;
    int s = elist[slot], d = edst[slot];
    const float4* pl = (const float4*)(xl + (size_t)s * HCc);
    const float4* pr = (const float4*)(xr + (size_t)d * HCc);
    const float4* at4 = (const float4*)att;
    bool tail = (j < 8);
    float4 ta[HEADSc], tb[HEADSc];
    #pragma unroll
    for (int h = 0; h < HEADSc; ++h) ta[h] = at4[h * 40 + j];
    if (tail) {
        #pragma unroll
        for (int h = 0; h < HEADSc; ++h) tb[h] = at4[h * 40 + 32 + j];
    }
    #pragma unroll
    for (int h = 0; h < HEADSc; ++h) {
        float4 a = pl[h * 40 + j];
        float4 b = pr[h * 40 + j];
        float4 t = ta[h];
        float m, lm, acc = 0.f;
        m = a.x + b.x; lm = fmaxf(m, 0.2f * m); acc = fmaf(lm, t.x, acc);
        m = a.y + b.y; lm = fmaxf(m, 0.2f * m); acc = fmaf(lm, t.y, acc);
        m = a.z + b.z; lm = fmaxf(m, 0.2f * m); acc = fmaf(lm, t.z, acc);
        m = a.w + b.w; lm = fmaxf(m, 0.2f * m); acc = fmaf(lm, t.w, acc);
        if (tail) {
            float4 a2 = pl[h * 40 + 32 + j];
            float4 b2 = pr[h * 40 + 32 + j];
            float4 t2 = tb[h];
            m = a2.x + b2.x; lm = fmaxf(m, 0.2f * m); acc = fmaf(lm, t2.x, acc);
            m = a2.y + b2.y; lm = fmaxf(m, 0.2f * m); acc = fmaf(lm, t2.y, acc);
            m = a2.z + b2.z; lm = fmaxf(m, 0.2f * m); acc = fmaf(lm, t2.z, acc);
            m = a2.w + b2.w; lm = fmaxf(m, 0.2f * m); acc = fmaf(lm, t2.w, acc);
        }
        #pragma unroll
        for (int ofs = 16; ofs >= 1; ofs >>= 1) acc += __shfl_xor(acc, ofs, 64);
        if (j == 0) scoreS[(size_t)slot * HEADSc + h] = acc;
    }
}

// ---------------------------------------------------------------------------
// per-dst softmax + weighted aggregation; thread t<200 owns float4 block t
// (channels 4t..4t+3, head = t/40 uniform). Writes g1 bf16 hi/lo splits.
// ---------------------------------------------------------------------------
#define ACHUNK 48
__global__ __launch_bounds__(256)
void gat_agg_kernel(const float* __restrict__ xl, const float* __restrict__ scoreS,
                    const int* __restrict__ elist, const int* __restrict__ off,
                    const float* __restrict__ gat_bias,
                    unsigned short* __restrict__ g1h, unsigned short* __restrict__ g1l) {
    int d = blockIdx.x;
    int t = threadIdx.x;
    __shared__ float mx_s[HEADSc], den_s[HEADSc];
    __shared__ float alpha_s[ACHUNK * HEADSc];
    __shared__ int src_s[ACHUNK];
    int e0 = off[d], e1 = off[d + 1];
    int cnt = e1 - e0;
    if (t < HEADSc) {
        float m = -1e30f;
        for (int e = 0; e < cnt; ++e)
            m = fmaxf(m, scoreS[(size_t)(e0 + e) * HEADSc + t]);
        float sden = 0.f;
        for (int e = 0; e < cnt; ++e)
            sden += __expf(scoreS[(size_t)(e0 + e) * HEADSc + t] - m);
        mx_s[t] = m;
        den_s[t] = sden;
    }
    __syncthreads();
    int hd = (t < 200) ? (t / 40) : 0;
    float4 acc = {0.f, 0.f, 0.f, 0.f};
    for (int base = 0; base < cnt; base += ACHUNK) {
        int nc = min(ACHUNK, cnt - base);
        if (t < nc * HEADSc) {
            int el = t / HEADSc, h = t % HEADSc;
            int slot = e0 + base + el;
            alpha_s[el * HEADSc + h] =
                __expf(scoreS[(size_t)slot * HEADSc + h] - mx_s[h]) / den_s[h];
            if (h == 0) src_s[el] = elist[slot];
        }
        __syncthreads();
        if (t < 200) {
            for (int el = 0; el < nc; ++el) {
                const float4* p = (const float4*)(xl + (size_t)src_s[el] * HCc);
                float al = alpha_s[el * HEADSc + hd];
                float4 v = p[t];
                acc.x = fmaf(al, v.x, acc.x);
                acc.y = fmaf(al, v.y, acc.y);
                acc.z = fmaf(al, v.z, acc.z);
                acc.w = fmaf(al, v.w, acc.w);
            }
        }
        __syncthreads();
    }
    if (t < 200) {
        float4 bv = ((const float4*)gat_bias)[t];
        ushort4 oh, ol;
        float v;
        v = fmaxf(acc.x + bv.x, 0.f); bsplit(v, oh.x, ol.x);
        v = fmaxf(acc.y + bv.y, 0.f); bsplit(v, oh.y, ol.y);
        v = fmaxf(acc.z + bv.z, 0.f); bsplit(v, oh.z, ol.z);
        v = fmaxf(acc.w + bv.w, 0.f); bsplit(v, oh.w, ol.w);
        *(ushort4*)(g1h + (size_t)d * HCc + 4 * t) = oh;
        *(ushort4*)(g1l + (size_t)d * HCc + 4 * t) = ol;
    }
}

// GCN aggregate, float4 form: g2[d] = relu(dinv[d] * sum dinv[src]*hg[src] + b)
__global__ __launch_bounds__(256)
void gcn_kernel(const float* __restrict__ hg, const float* __restrict__ dinv,
                const int* __restrict__ elist, const int* __restrict__ off,
                const float* __restrict__ b_gcn, float* __restrict__ g2) {
    int d = blockIdx.x;
    int t = threadIdx.x;
    __shared__ int src_s[64];
    __shared__ float w_s[64];
    int e0 = off[d], e1 = off[d + 1];
    int cnt = e1 - e0;
    float di = dinv[d];
    float4 acc = {0.f, 0.f, 0.f, 0.f};
    for (int base = 0; base < cnt; base += 64) {
        int nc = min(64, cnt - base);
        if (t < nc) {
            int s = elist[e0 + base + t];
            src_s[t] = s;
            w_s[t] = dinv[s];
        }
        __syncthreads();
        if (t < 200) {
            for (int el = 0; el < nc; ++el) {
                const float4* p = (const float4*)(hg + (size_t)src_s[el] * HCc);
                float w = w_s[el];
                float4 v = p[t];
                acc.x = fmaf(w, v.x, acc.x);
                acc.y = fmaf(w, v.y, acc.y);
                acc.z = fmaf(w, v.z, acc.z);
                acc.w = fmaf(w, v.w, acc.w);
            }
        }
        __syncthreads();
    }
    if (t < 200) {
        float4 bv = ((const float4*)b_gcn)[t];
        float4 o;
        o.x = fmaxf(acc.x * di + bv.x, 0.f);
        o.y = fmaxf(acc.y * di + bv.y, 0.f);
        o.z = fmaxf(acc.z * di + bv.z, 0.f);
        o.w = fmaxf(acc.w * di + bv.w, 0.f);
        *(float4*)(g2 + (size_t)d * HCc + 4 * t) = o;
    }
}

// graph boundaries in sorted batch (lower bound per graph)
__global__ void bounds_kernel(const int* __restrict__ batch, int* __restrict__ starts) {
    int g = threadIdx.x;
    if (g <= Gg) {
        if (g == Gg) { starts[Gg] = Nn; return; }
        int lo = 0, hi = Nn;
        while (lo < hi) {
            int mid = (lo + hi) >> 1;
            if (batch[mid] < g) lo = mid + 1; else hi = mid;
        }
        starts[g] = lo;
    }
}

// weighted mean + max pool per graph -> gfeat[G][1600]
__global__ __launch_bounds__(256)
void pool_kernel(const float* __restrict__ g2, const float* __restrict__ fw,
                 const int* __restrict__ starts, float* __restrict__ gfeat) {
    int g = blockIdx.x;
    int t = threadIdx.x;
    int n0 = starts[g], n1 = starts[g + 1];
    __shared__ float red[256];
    float wsum = 0.f;
    for (int n = n0 + t; n < n1; n += 256) wsum += fw[n];
    red[t] = wsum;
    __syncthreads();
    for (int ofs = 128; ofs > 0; ofs >>= 1) {
        if (t < ofs) red[t] += red[t + ofs];
        __syncthreads();
    }
    float wsg = fmaxf(red[0], 1e-6f);
    float s0 = 0.f, s1 = 0.f, s2 = 0.f, s3 = 0.f;
    float m0 = 0.f, m1 = 0.f, m2 = 0.f, m3 = 0.f;
    for (int n = n0; n < n1; ++n) {
        const float* p = g2 + (size_t)n * HCc;
        float w = fw[n];
        float v0 = p[t], v1 = p[t + 256], v2 = p[t + 512];
        s0 += v0 * w; s1 += v1 * w; s2 += v2 * w;
        m0 = fmaxf(m0, v0); m1 = fmaxf(m1, v1); m2 = fmaxf(m2, v2);
        if (t < 32) {
            float v3 = p[t + 768];
            s3 += v3 * w;
            m3 = fmaxf(m3, v3);
        }
    }
    float* gm = gfeat + (size_t)g * (2 * HCc);
    gm[t]       = s0 / wsg;  gm[HCc + t]       = m0;
    gm[t + 256] = s1 / wsg;  gm[HCc + t + 256] = m1;
    gm[t + 512] = s2 / wsg;  gm[HCc + t + 512] = m2;
    if (t < 32) { gm[t + 768] = s3 / wsg; gm[HCc + t + 768] = m3; }
}

// final MLP head: out = relu(relu(gfeat@W_fc + b_fc) @ W_out + b_out)
__global__ __launch_bounds__(128)
void head_kernel(const float* __restrict__ gfeat, const float* __restrict__ W_fc,
                 const float* __restrict__ b_fc, const float* __restrict__ W_out,
                 const float* __restrict__ b_out, float* __restrict__ out) {
    int g = blockIdx.x;
    int t = threadIdx.x;  // 128
    __shared__ float gf[2 * HCc];
    __shared__ float fc1[H2c];
    for (int i = t; i < 2 * HCc; i += 128) gf[i] = gfeat[(size_t)g * (2 * HCc) + i];
    __syncthreads();
    float a = b_fc[t];
    for (int k = 0; k < 2 * HCc; ++k) a += gf[k] * W_fc[(size_t)k * H2c + t];
    fc1[t] = fmaxf(a, 0.f);
    __syncthreads();
    if (t < OUTc) {
        float o = b_out[t];
        #pragma unroll 8
        for (int k = 0; k < H2c; ++k) o += fc1[k] * W_out[k * OUTc + t];
        out[g * OUTc + t] = fmaxf(o, 0.f);
    }
}

extern "C" void kernel_launch(void* const* d_in, const int* in_sizes, int n_in,
                              void* d_out, int out_size, void* d_ws, size_t ws_size,
                              hipStream_t stream) {
    (void)in_sizes; (void)n_in; (void)out_size; (void)ws_size;
    const float* x        = (const float*)d_in[0];
    const float* pe       = (const float*)d_in[1];
    const int*   eidx     = (const int*)d_in[2];
    const int*   batch    = (const int*)d_in[3];
    const float* fw       = (const float*)d_in[4];
    const float* W_pre    = (const float*)d_in[6];
    const float* b_pre    = (const float*)d_in[7];
    const float* W_l      = (const float*)d_in[8];
    const float* b_l      = (const float*)d_in[9];
    const float* W_r      = (const float*)d_in[10];
    const float* b_r      = (const float*)d_in[11];
    const float* att      = (const float*)d_in[12];
    const float* gat_bias = (const float*)d_in[13];
    const float* W_gcn    = (const float*)d_in[14];
    const float* b_gcn    = (const float*)d_in[15];
    const float* W_fc     = (const float*)d_in[16];
    const float* b_fc     = (const float*)d_in[17];
    const float* W_out    = (const float*)d_in[18];
    const float* b_out    = (const float*)d_in[19];
    float* out = (float*)d_out;

    // ---- workspace carving ----
    char* p = (char*)d_ws;
    auto alloc = [&](size_t bytes) {
        char* r = p;
        p += (bytes + 255) & ~(size_t)255;
        return r;
    };
    unsigned short* hh = (unsigned short*)alloc((size_t)Nn * Dd * 2 * 2);
    unsigned short* hl = hh + (size_t)Nn * Dd;
    float* bufA = (float*)alloc((size_t)Nn * HCc * 4);  // xl, later g2
    float* bufB = (float*)alloc((size_t)Nn * HCc * 4);  // xr, later g1 splits
    float* bufC = (float*)alloc((size_t)Nn * HCc * 4);  // x splits, later hg
    float* scoreS = (float*)alloc((size_t)ETot * HEADSc * 4);
    int*   cnt    = (int*)alloc((size_t)Nn * 4);
    int*   off    = (int*)alloc((size_t)(Nn + 1) * 4);
    int*   nxt    = (int*)alloc((size_t)Nn * 4);
    float* dinv   = (float*)alloc((size_t)Nn * 4);
    int*   elist  = (int*)alloc((size_t)ETot * 4);
    int*   edst   = (int*)alloc((size_t)ETot * 4);
    int*   starts = (int*)alloc((size_t)(Gg + 1) * 4);
    float* gfeat  = (float*)alloc((size_t)Gg * 2 * HCc * 4);
    int*   bsum   = (int*)alloc((size_t)NBLK * 4);
    unsigned short* WpreTh = (unsigned short*)alloc((size_t)Ff * H1c * 2 * 2);
    unsigned short* WpreTl = WpreTh + (size_t)Ff * H1c;
    unsigned short* WlTh   = (unsigned short*)alloc((size_t)Dd * HCc * 2 * 2);
    unsigned short* WlTl   = WlTh + (size_t)Dd * HCc;
    unsigned short* WrTh   = (unsigned short*)alloc((size_t)Dd * HCc * 2 * 2);
    unsigned short* WrTl   = WrTh + (size_t)Dd * HCc;
    unsigned short* WgTh   = (unsigned short*)alloc((size_t)HCc * HCc * 2 * 2);
    unsigned short* WgTl   = WgTh + (size_t)HCc * HCc;

    // aliases
    unsigned short* xh  = (unsigned short*)bufC;   // x splits live prep->GEMM1
    unsigned short* xlo = xh + (size_t)Nn * Ff;
    unsigned short* g1h = (unsigned short*)bufB;   // g1 splits live agg->GEMM4
    unsigned short* g1l = g1h + (size_t)Nn * HCc;

    // ---- CSR build ----
    hipMemsetAsync(cnt, 0, (size_t)Nn * 4, stream);
    count_kernel<<<(Ee + 255) / 256, 256, 0, stream>>>(eidx, cnt);
    scan1_kernel<<<NBLK, 256, 0, stream>>>(cnt, off, bsum);
    scan2_kernel<<<1, 64, 0, stream>>>(bsum);
    scan3_kernel<<<NBLK, 256, 0, stream>>>(cnt, off, nxt, dinv, bsum);
    scatter_kernel<<<(ETot + 255) / 256, 256, 0, stream>>>(eidx, nxt, elist, edst);

    // ---- splits ----
    asplit_kernel<<<(Nn * Ff / 4 + 255) / 256, 256, 0, stream>>>(x, xh, xlo, Nn * Ff / 4);
    wsplit_kernel<<<(Ff * H1c + 255) / 256, 256, 0, stream>>>(W_pre, WpreTh, WpreTl, Ff, H1c);
    wsplit_kernel<<<(Dd * HCc + 255) / 256, 256, 0, stream>>>(W_l, WlTh, WlTl, Dd, HCc);
    wsplit_kernel<<<(Dd * HCc + 255) / 256, 256, 0, stream>>>(W_r, WrTh, WrTl, Dd, HCc);
    wsplit_kernel<<<(HCc * HCc + 255) / 256, 256, 0, stream>>>(W_gcn, WgTh, WgTl, HCc, HCc);

    // ---- GEMM1: h = relu(x@W_pre + b_pre) -> h splits; then pe concat ----
    {
        dim3 grid((Nn + 127) / 128, (H1c + 127) / 128);
        gemm3_kernel<1><<<grid, 256, 0, stream>>>(
            xh, xlo, WpreTh, WpreTl, b_pre, nullptr, hh, hl,
            Nn, H1c, Ff, Ff, Dd, 1);
    }
    pe_copy_kernel<<<(Nn * PEc + 255) / 256, 256, 0, stream>>>(pe, hh, hl);

    // ---- GEMM2/3: xl = h@W_l + b_l ; xr = h@W_r + b_r (fp32 out) ----
    {
        dim3 grid((Nn + 127) / 128, (HCc + 127) / 128);
        gemm3_kernel<0><<<grid, 256, 0, stream>>>(
            hh, hl, WlTh, WlTl, b_l, bufA, nullptr, nullptr,
            Nn, HCc, Dd, Dd, HCc, 0);
        gemm3_kernel<0><<<grid, 256, 0, stream>>>(
            hh, hl, WrTh, WrTl, b_r, bufB, nullptr, nullptr,
            Nn, HCc, Dd, Dd, HCc, 0);
    }

    // ---- GATv2 scores (2 edges/wave), softmax + aggregate -> g1 splits ----
    score_kernel<<<(ETot / 2 + 3) / 4, 256, 0, stream>>>(bufA, bufB, att, elist, edst, scoreS);
    gat_agg_kernel<<<Nn, 256, 0, stream>>>(bufA, scoreS, elist, off, gat_bias, g1h, g1l);

    // ---- GEMM4: hg = g1 @ W_gcn -> bufC ----
    {
        dim3 grid((Nn + 127) / 128, (HCc + 127) / 128);
        gemm3_kernel<0><<<grid, 256, 0, stream>>>(
            g1h, g1l, WgTh, WgTl, nullptr, bufC, nullptr, nullptr,
            Nn, HCc, HCc, HCc, HCc, 0);
    }
    gcn_kernel<<<Nn, 256, 0, stream>>>(bufC, dinv, elist, off, b_gcn, bufA);

    // ---- pooling + head ----
    bounds_kernel<<<1, 128, 0, stream>>>(batch, starts);
    pool_kernel<<<Gg, 256, 0, stream>>>(bufA, fw, starts, gfeat);
    head_kernel<<<Gg, 128, 0, stream>>>(gfeat, W_fc, b_fc, W_out, b_out, out);
}

// Round 5
// 924.531 us; speedup vs baseline: 1.1379x; 1.1379x over previous
//
#include <hip/hip_runtime.h>
#include <hip/hip_bf16.h>

// Problem constants (fixed by reference)
#define Nn     20000
#define Ee     240000
#define Gg     64
#define Ff     768
#define H1c    128
#define PEc    32
#define Dd     160      // H1 + PE
#define HEADSc 5
#define HCc    800      // HEADS * D
#define H2c    128
#define OUTc   16
#define ETot   (Ee + Nn)  // edges + self loops = 260000
#define NEG_SLOPE_F 0.2f

typedef short bf16x8 __attribute__((ext_vector_type(8)));
typedef float f32x4 __attribute__((ext_vector_type(4)));
typedef unsigned int u32;

// ---- bf16 split helpers (round-to-nearest-even) ----
__device__ __forceinline__ unsigned short bf_hi_rn(float v) {
    unsigned int u = __float_as_uint(v);
    return (unsigned short)((u + 0x7FFFu + ((u >> 16) & 1u)) >> 16);
}
__device__ __forceinline__ void bsplit(float v, unsigned short& h, unsigned short& l) {
    unsigned short hh = bf_hi_rn(v);
    float hf = __uint_as_float(((unsigned int)hh) << 16);
    l = bf_hi_rn(v - hf);
    h = hh;
}

// async global->LDS, 16 B per lane; LDS dest = wave-uniform base + lane*16
__device__ __forceinline__ void gl_lds16(const unsigned short* g, unsigned short* l) {
    __builtin_amdgcn_global_load_lds(
        (const __attribute__((address_space(1))) u32*)g,
        (__attribute__((address_space(3))) u32*)l, 16, 0, 0);
}

// ---------------------------------------------------------------------------
// Split fp32 array -> bf16 hi/lo arrays (same layout), vectorized by 4
// ---------------------------------------------------------------------------
__global__ void asplit_kernel(const float* __restrict__ A, unsigned short* __restrict__ Ah,
                              unsigned short* __restrict__ Al, int total4) {
    int i = blockIdx.x * 256 + threadIdx.x;
    if (i < total4) {
        float4 v = ((const float4*)A)[i];
        ushort4 h4, l4;
        bsplit(v.x, h4.x, l4.x);
        bsplit(v.y, h4.y, l4.y);
        bsplit(v.z, h4.z, l4.z);
        bsplit(v.w, h4.w, l4.w);
        ((ushort4*)Ah)[i] = h4;
        ((ushort4*)Al)[i] = l4;
    }
}

// Weight transpose + split: W[K][N] fp32 -> Wh/Wl[N][K] bf16
__global__ void wsplit_kernel(const float* __restrict__ W, unsigned short* __restrict__ Wh,
                              unsigned short* __restrict__ Wl, int K, int N) {
    int i = blockIdx.x * 256 + threadIdx.x;
    if (i < K * N) {
        int k = i / N, n = i % N;
        unsigned short h, l;
        bsplit(W[i], h, l);
        Wh[(size_t)n * K + k] = h;
        Wl[(size_t)n * K + k] = l;
    }
}

// ---------------------------------------------------------------------------
// bf16x3 MFMA GEMM (unchanged from round 4)
// ---------------------------------------------------------------------------
#define KCHUNK 32

__device__ __forceinline__ void stage_tile(const unsigned short* __restrict__ gsrc, int ld,
                                           int row0, int maxRow, int k0,
                                           unsigned short* lbuf, int wave, int lane) {
    #pragma unroll
    for (int p = 0; p < 2; ++p) {
        int rb = wave * 16 + p * 64;
        int r = rb + (lane >> 2);
        int gr = min(row0 + r, maxRow);
        const unsigned short* g = gsrc + (size_t)gr * ld + k0 + (lane & 3) * 8;
        gl_lds16(g, lbuf + rb * 32);
    }
}

template<int OUT_MODE>
__global__ __launch_bounds__(256)
void gemm3_kernel(const unsigned short* __restrict__ Ah, const unsigned short* __restrict__ Al,
                  const unsigned short* __restrict__ Bh, const unsigned short* __restrict__ Bl,
                  const float* __restrict__ bias, float* __restrict__ C,
                  unsigned short* __restrict__ Ch, unsigned short* __restrict__ Cl,
                  int M, int N, int K, int lda, int ldc, int relu) {
    __shared__ __attribute__((aligned(16))) unsigned short As_h[128 * 32];
    __shared__ __attribute__((aligned(16))) unsigned short As_l[128 * 32];
    __shared__ __attribute__((aligned(16))) unsigned short Bs_h[128 * 32];
    __shared__ __attribute__((aligned(16))) unsigned short Bs_l[128 * 32];

    int tid = threadIdx.x;
    int m0 = blockIdx.x * 128, n0 = blockIdx.y * 128;
    int wave = tid >> 6, lane = tid & 63;
    int wm = (wave >> 1) * 64;
    int wn = (wave & 1) * 64;
    int fr = lane & 15;
    int fq = (lane >> 4) * 8;

    f32x4 acc[4][4] = {};

    for (int k0 = 0; k0 < K; k0 += KCHUNK) {
        stage_tile(Ah, lda, m0, M - 1, k0, As_h, wave, lane);
        stage_tile(Al, lda, m0, M - 1, k0, As_l, wave, lane);
        stage_tile(Bh, K,   n0, N - 1, k0, Bs_h, wave, lane);
        stage_tile(Bl, K,   n0, N - 1, k0, Bs_l, wave, lane);
        __syncthreads();

        bf16x8 a_h[4], a_l[4], b_h[4], b_l[4];
        #pragma unroll
        for (int i = 0; i < 4; ++i) {
            a_h[i] = *(const bf16x8*)&As_h[(wm + i * 16 + fr) * 32 + fq];
            a_l[i] = *(const bf16x8*)&As_l[(wm + i * 16 + fr) * 32 + fq];
        }
        #pragma unroll
        for (int j = 0; j < 4; ++j) {
            b_h[j] = *(const bf16x8*)&Bs_h[(wn + j * 16 + fr) * 32 + fq];
            b_l[j] = *(const bf16x8*)&Bs_l[(wn + j * 16 + fr) * 32 + fq];
        }
        #pragma unroll
        for (int j = 0; j < 4; ++j) {
            #pragma unroll
            for (int i = 0; i < 4; ++i) {
                acc[i][j] = __builtin_amdgcn_mfma_f32_16x16x32_bf16(a_h[i], b_h[j], acc[i][j], 0, 0, 0);
                acc[i][j] = __builtin_amdgcn_mfma_f32_16x16x32_bf16(a_h[i], b_l[j], acc[i][j], 0, 0, 0);
                acc[i][j] = __builtin_amdgcn_mfma_f32_16x16x32_bf16(a_l[i], b_h[j], acc[i][j], 0, 0, 0);
            }
        }
        __syncthreads();
    }

    int cr = (lane >> 4) * 4, cc = lane & 15;
    #pragma unroll
    for (int i = 0; i < 4; ++i) {
        #pragma unroll
        for (int j = 0; j < 4; ++j) {
            int c = n0 + wn + j * 16 + cc;
            if (c >= N) continue;
            float bv = bias ? bias[c] : 0.f;
            #pragma unroll
            for (int reg = 0; reg < 4; ++reg) {
                int r = m0 + wm + i * 16 + cr + reg;
                if (r >= M) continue;
                float v = acc[i][j][reg] + bv;
                if (relu) v = fmaxf(v, 0.f);
                if (OUT_MODE == 0) {
                    C[(size_t)r * ldc + c] = v;
                } else {
                    unsigned short hh, ll;
                    bsplit(v, hh, ll);
                    Ch[(size_t)r * ldc + c] = hh;
                    Cl[(size_t)r * ldc + c] = ll;
                }
            }
        }
    }
}

// copy pe_enc into h splits cols [128:160)
__global__ void pe_copy_kernel(const float* __restrict__ pe, unsigned short* __restrict__ hh,
                               unsigned short* __restrict__ hl) {
    int i = blockIdx.x * 256 + threadIdx.x;
    if (i < Nn * PEc) {
        int n = i / PEc, j = i % PEc;
        unsigned short h, l;
        bsplit(pe[i], h, l);
        hh[(size_t)n * Dd + H1c + j] = h;
        hl[(size_t)n * Dd + H1c + j] = l;
    }
}

// count in-degree (real edges only)
__global__ void count_kernel(const int* __restrict__ eidx, int* __restrict__ cnt) {
    int e = blockIdx.x * 256 + threadIdx.x;
    if (e < Ee) atomicAdd(&cnt[eidx[Ee + e]], 1);
}

// ---- multi-block exclusive scan over (cnt[i]+1) ----
#define NBLK 79  // ceil(20000/256)
__global__ void scan1_kernel(const int* __restrict__ cnt, int* __restrict__ off,
                             int* __restrict__ bsum) {
    __shared__ int sh[256];
    int t = threadIdx.x, i = blockIdx.x * 256 + t;
    int v = (i < Nn) ? (cnt[i] + 1) : 0;
    sh[t] = v;
    __syncthreads();
    for (int ofs = 1; ofs < 256; ofs <<= 1) {
        int add = (t >= ofs) ? sh[t - ofs] : 0;
        __syncthreads();
        sh[t] += add;
        __syncthreads();
    }
    if (i < Nn) off[i] = sh[t] - v;
    if (t == 255) bsum[blockIdx.x] = sh[255];
}
__global__ void scan2_kernel(int* __restrict__ bsum) {
    if (threadIdx.x == 0) {
        int acc = 0;
        for (int b = 0; b < NBLK; ++b) { int v = bsum[b]; bsum[b] = acc; acc += v; }
    }
}
__global__ void scan3_kernel(const int* __restrict__ cnt, int* __restrict__ off,
                             int* __restrict__ nxt, float* __restrict__ dinv,
                             const int* __restrict__ bsum) {
    int i = blockIdx.x * 256 + threadIdx.x;
    if (i < Nn) {
        int o = off[i] + bsum[blockIdx.x];
        off[i] = o;
        nxt[i] = o;
        dinv[i] = rsqrtf((float)(cnt[i] + 1));
    }
    if (i == 0) off[Nn] = ETot;
}

// scatter edges (and self loops) into CSR by dst
__global__ void scatter_kernel(const int* __restrict__ eidx, int* __restrict__ nxt,
                               int* __restrict__ elist, int* __restrict__ edst) {
    int e = blockIdx.x * 256 + threadIdx.x;
    if (e < ETot) {
        int s, d;
        if (e < Ee) { s = eidx[e]; d = eidx[Ee + e]; }
        else        { s = e - Ee; d = s; }
        int slot = atomicAdd(&nxt[d], 1);
        elist[slot] = s;
        edst[slot] = d;
    }
}

// ---------------------------------------------------------------------------
// FUSED GATv2: per-dst block computes edge scores AND aggregates x_l[src]
// in ONE pass over the gathered rows, using online softmax (flash-style).
// x_r[dst] and att stay in registers; running (m, den, scale, w) per head in
// LDS. Writes g1 as bf16 hi/lo splits.
// ---------------------------------------------------------------------------
#define SCHUNK 64
__global__ __launch_bounds__(256)
void fused_gat_kernel(const float* __restrict__ xl, const float* __restrict__ xr,
                      const float* __restrict__ att, const int* __restrict__ elist,
                      const int* __restrict__ off, const float* __restrict__ gat_bias,
                      unsigned short* __restrict__ g1h, unsigned short* __restrict__ g1l) {
    int d = blockIdx.x;
    int t = threadIdx.x;
    __shared__ float sh_red[256];
    __shared__ float sh_scale[HEADSc], sh_w[HEADSc], sh_m[HEADSc], sh_den[HEADSc];
    __shared__ int sh_src[SCHUNK];
    int e0 = off[d], e1 = off[d + 1];
    int cnt = e1 - e0;
    bool act = t < 200;
    int hd = act ? (t / 40) : 0;
    float4 vr = {0.f, 0.f, 0.f, 0.f}, va = {0.f, 0.f, 0.f, 0.f};
    if (act) {
        vr = ((const float4*)(xr + (size_t)d * HCc))[t];
        va = ((const float4*)att)[t];
    }
    if (t < HEADSc) { sh_m[t] = -1e30f; sh_den[t] = 0.f; }
    float4 acc = {0.f, 0.f, 0.f, 0.f};
    for (int base = 0; base < cnt; base += SCHUNK) {
        int nc = min(SCHUNK, cnt - base);
        if (t < nc) sh_src[t] = elist[e0 + base + t];
        __syncthreads();
        for (int el = 0; el < nc; ++el) {
            float4 vl = {0.f, 0.f, 0.f, 0.f};
            if (act) vl = ((const float4*)(xl + (size_t)sh_src[el] * HCc))[t];
            float p = 0.f, m, lm;
            m = vl.x + vr.x; lm = fmaxf(m, 0.2f * m); p = fmaf(lm, va.x, p);
            m = vl.y + vr.y; lm = fmaxf(m, 0.2f * m); p = fmaf(lm, va.y, p);
            m = vl.z + vr.z; lm = fmaxf(m, 0.2f * m); p = fmaf(lm, va.z, p);
            m = vl.w + vr.w; lm = fmaxf(m, 0.2f * m); p = fmaf(lm, va.w, p);
            sh_red[t] = act ? p : 0.f;
            __syncthreads();
            if (t < HEADSc) {
                float s = 0.f;
                const float* pr = sh_red + t * 40;
                #pragma unroll
                for (int q = 0; q < 40; ++q) s += pr[q];
                float mo = sh_m[t];
                float mn = fmaxf(mo, s);
                float sc = __expf(mo - mn);   // 0 on first edge (mo = -1e30)
                float w  = __expf(s - mn);
                sh_den[t] = sh_den[t] * sc + w;
                sh_m[t] = mn;
                sh_scale[t] = sc;
                sh_w[t] = w;
            }
            __syncthreads();
            if (act) {
                float sc = sh_scale[hd], w = sh_w[hd];
                acc.x = fmaf(acc.x, sc, w * vl.x);
                acc.y = fmaf(acc.y, sc, w * vl.y);
                acc.z = fmaf(acc.z, sc, w * vl.z);
                acc.w = fmaf(acc.w, sc, w * vl.w);
            }
        }
    }
    if (act) {
        float inv = 1.f / sh_den[hd];   // den > 0 (self-loop guarantees an edge)
        float4 bv = ((const float4*)gat_bias)[t];
        ushort4 oh, ol;
        float v;
        v = fmaxf(fmaf(acc.x, inv, bv.x), 0.f); bsplit(v, oh.x, ol.x);
        v = fmaxf(fmaf(acc.y, inv, bv.y), 0.f); bsplit(v, oh.y, ol.y);
        v = fmaxf(fmaf(acc.z, inv, bv.z), 0.f); bsplit(v, oh.z, ol.z);
        v = fmaxf(fmaf(acc.w, inv, bv.w), 0.f); bsplit(v, oh.w, ol.w);
        *(ushort4*)(g1h + (size_t)d * HCc + 4 * t) = oh;
        *(ushort4*)(g1l + (size_t)d * HCc + 4 * t) = ol;
    }
}

// GCN aggregate, float4 form: g2[d] = relu(dinv[d] * sum dinv[src]*hg[src] + b)
__global__ __launch_bounds__(256)
void gcn_kernel(const float* __restrict__ hg, const float* __restrict__ dinv,
                const int* __restrict__ elist, const int* __restrict__ off,
                const float* __restrict__ b_gcn, float* __restrict__ g2) {
    int d = blockIdx.x;
    int t = threadIdx.x;
    __shared__ int src_s[64];
    __shared__ float w_s[64];
    int e0 = off[d], e1 = off[d + 1];
    int cnt = e1 - e0;
    float di = dinv[d];
    float4 acc = {0.f, 0.f, 0.f, 0.f};
    for (int base = 0; base < cnt; base += 64) {
        int nc = min(64, cnt - base);
        if (t < nc) {
            int s = elist[e0 + base + t];
            src_s[t] = s;
            w_s[t] = dinv[s];
        }
        __syncthreads();
        if (t < 200) {
            for (int el = 0; el < nc; ++el) {
                const float4* p = (const float4*)(hg + (size_t)src_s[el] * HCc);
                float w = w_s[el];
                float4 v = p[t];
                acc.x = fmaf(w, v.x, acc.x);
                acc.y = fmaf(w, v.y, acc.y);
                acc.z = fmaf(w, v.z, acc.z);
                acc.w = fmaf(w, v.w, acc.w);
            }
        }
        __syncthreads();
    }
    if (t < 200) {
        float4 bv = ((const float4*)b_gcn)[t];
        float4 o;
        o.x = fmaxf(acc.x * di + bv.x, 0.f);
        o.y = fmaxf(acc.y * di + bv.y, 0.f);
        o.z = fmaxf(acc.z * di + bv.z, 0.f);
        o.w = fmaxf(acc.w * di + bv.w, 0.f);
        *(float4*)(g2 + (size_t)d * HCc + 4 * t) = o;
    }
}

// graph boundaries in sorted batch (lower bound per graph)
__global__ void bounds_kernel(const int* __restrict__ batch, int* __restrict__ starts) {
    int g = threadIdx.x;
    if (g <= Gg) {
        if (g == Gg) { starts[Gg] = Nn; return; }
        int lo = 0, hi = Nn;
        while (lo < hi) {
            int mid = (lo + hi) >> 1;
            if (batch[mid] < g) lo = mid + 1; else hi = mid;
        }
        starts[g] = lo;
    }
}

// weighted mean + max pool per graph -> gfeat[G][1600]
__global__ __launch_bounds__(256)
void pool_kernel(const float* __restrict__ g2, const float* __restrict__ fw,
                 const int* __restrict__ starts, float* __restrict__ gfeat) {
    int g = blockIdx.x;
    int t = threadIdx.x;
    int n0 = starts[g], n1 = starts[g + 1];
    __shared__ float red[256];
    float wsum = 0.f;
    for (int n = n0 + t; n < n1; n += 256) wsum += fw[n];
    red[t] = wsum;
    __syncthreads();
    for (int ofs = 128; ofs > 0; ofs >>= 1) {
        if (t < ofs) red[t] += red[t + ofs];
        __syncthreads();
    }
    float wsg = fmaxf(red[0], 1e-6f);
    float s0 = 0.f, s1 = 0.f, s2 = 0.f, s3 = 0.f;
    float m0 = 0.f, m1 = 0.f, m2 = 0.f, m3 = 0.f;
    for (int n = n0; n < n1; ++n) {
        const float* p = g2 + (size_t)n * HCc;
        float w = fw[n];
        float v0 = p[t], v1 = p[t + 256], v2 = p[t + 512];
        s0 += v0 * w; s1 += v1 * w; s2 += v2 * w;
        m0 = fmaxf(m0, v0); m1 = fmaxf(m1, v1); m2 = fmaxf(m2, v2);
        if (t < 32) {
            float v3 = p[t + 768];
            s3 += v3 * w;
            m3 = fmaxf(m3, v3);
        }
    }
    float* gm = gfeat + (size_t)g * (2 * HCc);
    gm[t]       = s0 / wsg;  gm[HCc + t]       = m0;
    gm[t + 256] = s1 / wsg;  gm[HCc + t + 256] = m1;
    gm[t + 512] = s2 / wsg;  gm[HCc + t + 512] = m2;
    if (t < 32) { gm[t + 768] = s3 / wsg; gm[HCc + t + 768] = m3; }
}

// final MLP head: out = relu(relu(gfeat@W_fc + b_fc) @ W_out + b_out)
__global__ __launch_bounds__(128)
void head_kernel(const float* __restrict__ gfeat, const float* __restrict__ W_fc,
                 const float* __restrict__ b_fc, const float* __restrict__ W_out,
                 const float* __restrict__ b_out, float* __restrict__ out) {
    int g = blockIdx.x;
    int t = threadIdx.x;  // 128
    __shared__ float gf[2 * HCc];
    __shared__ float fc1[H2c];
    for (int i = t; i < 2 * HCc; i += 128) gf[i] = gfeat[(size_t)g * (2 * HCc) + i];
    __syncthreads();
    float a = b_fc[t];
    for (int k = 0; k < 2 * HCc; ++k) a += gf[k] * W_fc[(size_t)k * H2c + t];
    fc1[t] = fmaxf(a, 0.f);
    __syncthreads();
    if (t < OUTc) {
        float o = b_out[t];
        #pragma unroll 8
        for (int k = 0; k < H2c; ++k) o += fc1[k] * W_out[k * OUTc + t];
        out[g * OUTc + t] = fmaxf(o, 0.f);
    }
}

extern "C" void kernel_launch(void* const* d_in, const int* in_sizes, int n_in,
                              void* d_out, int out_size, void* d_ws, size_t ws_size,
                              hipStream_t stream) {
    (void)in_sizes; (void)n_in; (void)out_size; (void)ws_size;
    const float* x        = (const float*)d_in[0];
    const float* pe       = (const float*)d_in[1];
    const int*   eidx     = (const int*)d_in[2];
    const int*   batch    = (const int*)d_in[3];
    const float* fw       = (const float*)d_in[4];
    const float* W_pre    = (const float*)d_in[6];
    const float* b_pre    = (const float*)d_in[7];
    const float* W_l      = (const float*)d_in[8];
    const float* b_l      = (const float*)d_in[9];
    const float* W_r      = (const float*)d_in[10];
    const float* b_r      = (const float*)d_in[11];
    const float* att      = (const float*)d_in[12];
    const float* gat_bias = (const float*)d_in[13];
    const float* W_gcn    = (const float*)d_in[14];
    const float* b_gcn    = (const float*)d_in[15];
    const float* W_fc     = (const float*)d_in[16];
    const float* b_fc     = (const float*)d_in[17];
    const float* W_out    = (const float*)d_in[18];
    const float* b_out    = (const float*)d_in[19];
    float* out = (float*)d_out;

    // ---- workspace carving ----
    char* p = (char*)d_ws;
    auto alloc = [&](size_t bytes) {
        char* r = p;
        p += (bytes + 255) & ~(size_t)255;
        return r;
    };
    unsigned short* hh = (unsigned short*)alloc((size_t)Nn * Dd * 2 * 2);
    unsigned short* hl = hh + (size_t)Nn * Dd;
    float* bufA = (float*)alloc((size_t)Nn * HCc * 4);  // xl, later hg
    float* bufB = (float*)alloc((size_t)Nn * HCc * 4);  // xr, later g2
    float* bufC = (float*)alloc((size_t)Nn * HCc * 4);  // x splits, later g1 splits
    int*   cnt    = (int*)alloc((size_t)Nn * 4);
    int*   off    = (int*)alloc((size_t)(Nn + 1) * 4);
    int*   nxt    = (int*)alloc((size_t)Nn * 4);
    float* dinv   = (float*)alloc((size_t)Nn * 4);
    int*   elist  = (int*)alloc((size_t)ETot * 4);
    int*   edst   = (int*)alloc((size_t)ETot * 4);
    int*   starts = (int*)alloc((size_t)(Gg + 1) * 4);
    float* gfeat  = (float*)alloc((size_t)Gg * 2 * HCc * 4);
    int*   bsum   = (int*)alloc((size_t)NBLK * 4);
    unsigned short* WpreTh = (unsigned short*)alloc((size_t)Ff * H1c * 2 * 2);
    unsigned short* WpreTl = WpreTh + (size_t)Ff * H1c;
    unsigned short* WlTh   = (unsigned short*)alloc((size_t)Dd * HCc * 2 * 2);
    unsigned short* WlTl   = WlTh + (size_t)Dd * HCc;
    unsigned short* WrTh   = (unsigned short*)alloc((size_t)Dd * HCc * 2 * 2);
    unsigned short* WrTl   = WrTh + (size_t)Dd * HCc;
    unsigned short* WgTh   = (unsigned short*)alloc((size_t)HCc * HCc * 2 * 2);
    unsigned short* WgTl   = WgTh + (size_t)HCc * HCc;

    // aliases (disjoint lifetimes within bufC)
    unsigned short* xh  = (unsigned short*)bufC;   // x splits: prep -> GEMM1
    unsigned short* xlo = xh + (size_t)Nn * Ff;
    unsigned short* g1h = (unsigned short*)bufC;   // g1 splits: fused agg -> GEMM4
    unsigned short* g1l = g1h + (size_t)Nn * HCc;

    // ---- CSR build ----
    hipMemsetAsync(cnt, 0, (size_t)Nn * 4, stream);
    count_kernel<<<(Ee + 255) / 256, 256, 0, stream>>>(eidx, cnt);
    scan1_kernel<<<NBLK, 256, 0, stream>>>(cnt, off, bsum);
    scan2_kernel<<<1, 64, 0, stream>>>(bsum);
    scan3_kernel<<<NBLK, 256, 0, stream>>>(cnt, off, nxt, dinv, bsum);
    scatter_kernel<<<(ETot + 255) / 256, 256, 0, stream>>>(eidx, nxt, elist, edst);

    // ---- splits ----
    asplit_kernel<<<(Nn * Ff / 4 + 255) / 256, 256, 0, stream>>>(x, xh, xlo, Nn * Ff / 4);
    wsplit_kernel<<<(Ff * H1c + 255) / 256, 256, 0, stream>>>(W_pre, WpreTh, WpreTl, Ff, H1c);
    wsplit_kernel<<<(Dd * HCc + 255) / 256, 256, 0, stream>>>(W_l, WlTh, WlTl, Dd, HCc);
    wsplit_kernel<<<(Dd * HCc + 255) / 256, 256, 0, stream>>>(W_r, WrTh, WrTl, Dd, HCc);
    wsplit_kernel<<<(HCc * HCc + 255) / 256, 256, 0, stream>>>(W_gcn, WgTh, WgTl, HCc, HCc);

    // ---- GEMM1: h = relu(x@W_pre + b_pre) -> h splits; then pe concat ----
    {
        dim3 grid((Nn + 127) / 128, (H1c + 127) / 128);
        gemm3_kernel<1><<<grid, 256, 0, stream>>>(
            xh, xlo, WpreTh, WpreTl, b_pre, nullptr, hh, hl,
            Nn, H1c, Ff, Ff, Dd, 1);
    }
    pe_copy_kernel<<<(Nn * PEc + 255) / 256, 256, 0, stream>>>(pe, hh, hl);

    // ---- GEMM2/3: xl = h@W_l + b_l -> bufA ; xr = h@W_r + b_r -> bufB ----
    {
        dim3 grid((Nn + 127) / 128, (HCc + 127) / 128);
        gemm3_kernel<0><<<grid, 256, 0, stream>>>(
            hh, hl, WlTh, WlTl, b_l, bufA, nullptr, nullptr,
            Nn, HCc, Dd, Dd, HCc, 0);
        gemm3_kernel<0><<<grid, 256, 0, stream>>>(
            hh, hl, WrTh, WrTl, b_r, bufB, nullptr, nullptr,
            Nn, HCc, Dd, Dd, HCc, 0);
    }

    // ---- FUSED GATv2: scores + online softmax + aggregate -> g1 (bufC) ----
    fused_gat_kernel<<<Nn, 256, 0, stream>>>(bufA, bufB, att, elist, off,
                                             gat_bias, g1h, g1l);

    // ---- GEMM4: hg = g1 @ W_gcn -> bufA (xl dead) ----
    {
        dim3 grid((Nn + 127) / 128, (HCc + 127) / 128);
        gemm3_kernel<0><<<grid, 256, 0, stream>>>(
            g1h, g1l, WgTh, WgTl, nullptr, bufA, nullptr, nullptr,
            Nn, HCc, HCc, HCc, HCc, 0);
    }
    // ---- GCN aggregate -> g2 (bufB, xr dead) ----
    gcn_kernel<<<Nn, 256, 0, stream>>>(bufA, dinv, elist, off, b_gcn, bufB);

    // ---- pooling + head ----
    bounds_kernel<<<1, 128, 0, stream>>>(batch, starts);
    pool_kernel<<<Gg, 256, 0, stream>>>(bufB, fw, starts, gfeat);
    head_kernel<<<Gg, 128, 0, stream>>>(gfeat, W_fc, b_fc, W_out, b_out, out);
}